// Round 1
// baseline (1798.146 us; speedup 1.0000x reference)
//
#include <hip/hip_runtime.h>
#include <math.h>

#define L    2048
#define NCOL 4096
#define NG   1024
#define N3   3072
#define T    512
#define EPT  8            // NCOL / T
#define FEPS 1.1920929e-07f

__device__ __forceinline__ int lower_bound_f(const float* a, int n, float v) {
  // exact replica of numpy's npy_binsearch (side='left')
  int lo = 0, hi = n;
  while (lo < hi) {
    int mid = (lo + hi) >> 1;
    if (a[mid] < v) lo = mid + 1; else hi = mid;
  }
  return lo;
}

__global__ __launch_bounds__(T) void lcot_rows(const float* __restrict__ X,
                                               const float* __restrict__ W,
                                               float* __restrict__ rowsum) {
  extern __shared__ char smem[];
  unsigned long long* su = (unsigned long long*)smem;  // 4096 * 8 B (sort keys)
  float* xs   = (float*)smem;                          // alias after sort: 4096 f
  float* ys   = xs + NCOL;                             // alias after sort: 4096 f
  float* ecdf = (float*)(smem + (size_t)NCOL * 8);     // 3072 f

  __shared__ float chunk[T];
  __shared__ float redA[T / 64], redB[T / 64];
  __shared__ float s_alpha;

  const int row = blockIdx.x;
  const int t = threadIdx.x;
  const float* xr = X + (size_t)row * NCOL;
  const float* wr = W + (size_t)row * NCOL;

  // ---- load, pack (keybits<<32)|idx, alpha partial sums ----
  float sxw = 0.f, sw = 0.f;
#pragma unroll
  for (int s = 0; s < EPT; ++s) {
    int i = t + s * T;
    float xv = xr[i];
    float wv = wr[i];
    sxw += xv * wv;
    sw  += wv;
    su[i] = ((unsigned long long)__float_as_uint(xv) << 32) | (unsigned)i;
  }
#pragma unroll
  for (int off = 32; off > 0; off >>= 1) {
    sxw += __shfl_down(sxw, off);
    sw  += __shfl_down(sw, off);
  }
  if ((t & 63) == 0) { redA[t >> 6] = sxw; redB[t >> 6] = sw; }
  __syncthreads();
  if (t == 0) {
    float a = 0.f, b = 0.f;
#pragma unroll
    for (int i = 0; i < T / 64; ++i) { a += redA[i]; b += redB[i]; }
    s_alpha = a / b - 0.5f;
  }
  __syncthreads();  // also orders su[] writes before sort

  // ---- bitonic sort (ascending u64: stable sort on x) ----
  for (int kk = 2; kk <= NCOL; kk <<= 1) {
    for (int j = kk >> 1; j > 0; j >>= 1) {
#pragma unroll
      for (int s = 0; s < EPT; ++s) {
        int idx = t + s * T;
        int ixj = idx ^ j;
        if (ixj > idx) {
          unsigned long long a = su[idx];
          unsigned long long b = su[ixj];
          bool up = ((idx & kk) == 0);
          if (up ? (a > b) : (a < b)) { su[idx] = b; su[ixj] = a; }
        }
      }
      __syncthreads();
    }
  }

  // ---- unpack: consecutive 8/thread; gather w; chunk-local inclusive scan ----
  unsigned long long r[EPT];
#pragma unroll
  for (int i = 0; i < EPT; ++i) r[i] = su[t * EPT + i];
  __syncthreads();  // all reads of su done before alias (xs/ys) writes

  float sc[EPT];
  float run = 0.f;
#pragma unroll
  for (int i = 0; i < EPT; ++i) {
    unsigned idx = (unsigned)(r[i] & 0xffffffffu);
    float wv = wr[idx];            // 16 KB row: L1/L2-hot gather
    run += wv;
    sc[i] = run;
    xs[t * EPT + i] = __uint_as_float((unsigned)(r[i] >> 32));
  }
  chunk[t] = run;
  __syncthreads();
  // Hillis-Steele inclusive scan over 512 chunk totals
  for (int off = 1; off < T; off <<= 1) {
    float add = (t >= off) ? chunk[t - off] : 0.f;
    float cur = chunk[t];
    __syncthreads();
    chunk[t] = cur + add;
    __syncthreads();
  }
  float pre = (t > 0) ? chunk[t - 1] : 0.f;
#pragma unroll
  for (int i = 0; i < EPT; ++i) ys[t * EPT + i] = sc[i] + pre;
  __syncthreads();

  // ---- stage 1: ecdf[j] = floor(xnew) + interp1d(xs, ys, frac(xnew)) ----
  for (int j = t; j < N3; j += T) {
    float xnew = -1.0f + (3.0f * (float)j) / 3071.0f;  // exact 2.0 at j=3071
    float ix = floorf(xnew);
    float rest = xnew - ix;
    int lo = lower_bound_f(xs, NCOL, rest);
    int ind = lo - 1;
    ind = ind < 0 ? 0 : (ind > NCOL - 2 ? NCOL - 2 : ind);
    float x0 = xs[ind], x1v = xs[ind + 1];
    float y0 = ys[ind], y1v = ys[ind + 1];
    float slope = (y1v - y0) / (FEPS + (x1v - x0));
    ecdf[j] = ix + (y0 + slope * (rest - x0));
  }
  __syncthreads();

  // ---- stage 2: embedd = interp1d(ecdf, xnew, grid - alpha) - grid; sum m^2 ----
  float alpha = s_alpha;
  float acc = 0.f;
#pragma unroll
  for (int s = 0; s < NG / T; ++s) {
    int k = t + s * T;
    float xg = (float)k / 1024.0f;
    float q = xg - alpha;
    int lo = lower_bound_f(ecdf, N3, q);
    int ind = lo - 1;
    ind = ind < 0 ? 0 : (ind > N3 - 2 ? N3 - 2 : ind);
    float e0 = ecdf[ind], e1 = ecdf[ind + 1];
    float y0 = -1.0f + (3.0f * (float)ind) / 3071.0f;
    float y1 = -1.0f + (3.0f * (float)(ind + 1)) / 3071.0f;
    float slope = (y1 - y0) / (FEPS + (e1 - e0));
    float emb = y0 + slope * (q - e0) - xg;
    float a = fabsf(emb);
    float m = fminf(a, 1.0f - a);
    acc += m * m;
  }
#pragma unroll
  for (int off = 32; off > 0; off >>= 1) acc += __shfl_down(acc, off);
  if ((t & 63) == 0) redA[t >> 6] = acc;
  __syncthreads();
  if (t == 0) {
    float s = 0.f;
#pragma unroll
    for (int i = 0; i < T / 64; ++i) s += redA[i];
    rowsum[row] = s;
  }
}

__global__ __launch_bounds__(256) void lcot_final(const float* __restrict__ rowsum,
                                                  float* __restrict__ out) {
  __shared__ float red[4];
  int t = threadIdx.x;
  float s = 0.f;
  for (int i = t; i < L; i += 256) s += rowsum[i];
#pragma unroll
  for (int off = 32; off > 0; off >>= 1) s += __shfl_down(s, off);
  if ((t & 63) == 0) red[t >> 6] = s;
  __syncthreads();
  if (t == 0) {
    float tot = red[0] + red[1] + red[2] + red[3];
    out[0] = sqrtf(tot / (float)L + 1e-8f);
  }
}

extern "C" void kernel_launch(void* const* d_in, const int* in_sizes, int n_in,
                              void* d_out, int out_size, void* d_ws, size_t ws_size,
                              hipStream_t stream) {
  const float* X = (const float*)d_in[0];
  const float* W = (const float*)d_in[1];
  float* rowsum = (float*)d_ws;  // 2048 floats
  size_t shbytes = (size_t)NCOL * 8 + (size_t)N3 * 4;  // 45056 B dynamic LDS
  hipLaunchKernelGGL(lcot_rows, dim3(L), dim3(T), shbytes, stream, X, W, rowsum);
  hipLaunchKernelGGL(lcot_final, dim3(1), dim3(256), 0, stream,
                     (const float*)rowsum, (float*)d_out);
}

// Round 2
// 361.457 us; speedup vs baseline: 4.9747x; 4.9747x over previous
//
#include <hip/hip_runtime.h>
#include <math.h>

#define L    2048
#define NCOL 4096
#define NG   1024
#define N3   3072
#define T    256
#define EPT  16           // NCOL / T
#define FEPS 1.1920929e-07f

typedef unsigned long long u64;

__device__ __forceinline__ void cex(u64 &a, u64 &b, bool up) {
  // a sits at the lower network index; ascending (up) wants a<=b
  u64 lo = a < b ? a : b;
  u64 hi = a < b ? b : a;
  a = up ? lo : hi;
  b = up ? hi : lo;
}

// j = 8,4,2,1 passes, direction uniform across the thread's 16 elements
__device__ __forceinline__ void intra4(u64 *k, bool up) {
#pragma unroll
  for (int e = 0; e < 8; ++e) cex(k[e], k[e + 8], up);
#pragma unroll
  for (int g = 0; g < 16; g += 8) {
#pragma unroll
    for (int d = 0; d < 4; ++d) cex(k[g + d], k[g + d + 4], up);
  }
#pragma unroll
  for (int g = 0; g < 16; g += 4) {
    cex(k[g], k[g + 2], up);
    cex(k[g + 1], k[g + 3], up);
  }
#pragma unroll
  for (int g = 0; g < 16; g += 2) cex(k[g], k[g + 1], up);
}

__device__ __forceinline__ int lower_bound_f(const float* a, int lo, int hi, float v) {
  // exact replica of numpy's npy_binsearch (side='left') on [lo,hi)
  while (lo < hi) {
    int mid = (lo + hi) >> 1;
    if (a[mid] < v) lo = mid + 1; else hi = mid;
  }
  return lo;
}

__global__ __launch_bounds__(T) void lcot_rows(const float* __restrict__ X,
                                               const float* __restrict__ W,
                                               float* __restrict__ rowsum) {
  extern __shared__ char smem[];
  u64*   su   = (u64*)smem;                             // 32 KB sort exchange buf
  float* xs   = (float*)smem;                           // alias after sort
  float* ys   = xs + NCOL;                              // alias after sort
  float* ecdf = (float*)(smem + (size_t)NCOL * 8);      // 12 KB
  int*   lut  = (int*)(smem + (size_t)NCOL * 8 + (size_t)N3 * 4);  // 257 ints

  __shared__ float red1[4], red2[4], wtot[4];
  __shared__ float s_alpha;

  const int tid  = threadIdx.x;
  const int lane = tid & 63;
  const int wave = tid >> 6;
  const int row  = blockIdx.x;
  const float* xr = X + (size_t)row * NCOL;
  const float* wr = W + (size_t)row * NCOL;

  // ---- load 16 consecutive elements, pack keys, alpha partials ----
  u64 key[EPT];
  float sxw = 0.f, sw = 0.f;
  const float4* xr4 = (const float4*)xr;
  const float4* wr4 = (const float4*)wr;
#pragma unroll
  for (int c = 0; c < 4; ++c) {
    float4 xv = xr4[tid * 4 + c];
    float4 wv = wr4[tid * 4 + c];
    sxw += xv.x * wv.x + xv.y * wv.y + xv.z * wv.z + xv.w * wv.w;
    sw  += wv.x + wv.y + wv.z + wv.w;
    int b = 16 * tid + 4 * c;
    key[4*c+0] = ((u64)__float_as_uint(xv.x) << 32) | (unsigned)(b + 0);
    key[4*c+1] = ((u64)__float_as_uint(xv.y) << 32) | (unsigned)(b + 1);
    key[4*c+2] = ((u64)__float_as_uint(xv.z) << 32) | (unsigned)(b + 2);
    key[4*c+3] = ((u64)__float_as_uint(xv.w) << 32) | (unsigned)(b + 3);
  }
#pragma unroll
  for (int off = 32; off > 0; off >>= 1) {
    sxw += __shfl_down(sxw, off);
    sw  += __shfl_down(sw, off);
  }
  if (lane == 0) { red1[wave] = sxw; red2[wave] = sw; }
  __syncthreads();
  if (tid == 0) {
    float a = red1[0] + red1[1] + red1[2] + red1[3];
    float b = red2[0] + red2[1] + red2[2] + red2[3];
    s_alpha = a / b - 0.5f;
  }

  // ---- bitonic sort: register passes + wave shuffles + 3 LDS passes ----
  // kk = 2 (j=1)
#pragma unroll
  for (int g = 0; g < 16; g += 2) cex(key[g], key[g + 1], ((g & 2) == 0));
  // kk = 4 (j=2,1)
#pragma unroll
  for (int g = 0; g < 16; g += 4) {
    bool up = ((g & 4) == 0);
    cex(key[g], key[g + 2], up); cex(key[g + 1], key[g + 3], up);
  }
#pragma unroll
  for (int g = 0; g < 16; g += 2) {
    bool up = ((g & 4) == 0);
    cex(key[g], key[g + 1], up);
  }
  // kk = 8 (j=4,2,1)
#pragma unroll
  for (int g = 0; g < 16; g += 8) {
    bool up = ((g & 8) == 0);
#pragma unroll
    for (int d = 0; d < 4; ++d) cex(key[g + d], key[g + d + 4], up);
  }
#pragma unroll
  for (int g = 0; g < 16; g += 4) {
    bool up = ((g & 8) == 0);
    cex(key[g], key[g + 2], up); cex(key[g + 1], key[g + 3], up);
  }
#pragma unroll
  for (int g = 0; g < 16; g += 2) {
    bool up = ((g & 8) == 0);
    cex(key[g], key[g + 1], up);
  }
  // kk = 16 (j=8..1, direction uniform per thread)
  intra4(key, (tid & 1) == 0);
  // kk = 32 .. 4096
  for (int kk = 32; kk <= NCOL; kk <<= 1) {
    bool up = (((unsigned)(tid << 4) & (unsigned)kk) == 0);
    for (int j = kk >> 1; j >= 16; j >>= 1) {
      int p = j >> 4;  // thread-xor distance
      if (j >= 1024) {
        // cross-wave: LDS exchange (p = 64 or 128), xor-swizzled addresses
        int sw_ = tid & 15;
#pragma unroll
        for (int c = 0; c < 16; ++c) su[16 * tid + (c ^ sw_)] = key[c];
        __syncthreads();
        bool keep_min = (((tid & p) == 0) == up);
        int pb = 16 * (tid ^ p);  // (tid^p)&15 == tid&15, same swizzle
#pragma unroll
        for (int c = 0; c < 16; ++c) {
          u64 o  = su[pb + (c ^ sw_)];
          u64 mn = key[c] < o ? key[c] : o;
          u64 mx = key[c] < o ? o : key[c];
          key[c] = keep_min ? mn : mx;
        }
        __syncthreads();
      } else {
        // intra-wave64 shuffle exchange (p = 1..32)
        bool keep_min = (((tid & p) == 0) == up);
#pragma unroll
        for (int c = 0; c < 16; ++c) {
          u64 o  = __shfl_xor(key[c], p);
          u64 mn = key[c] < o ? key[c] : o;
          u64 mx = key[c] < o ? o : key[c];
          key[c] = keep_min ? mn : mx;
        }
      }
    }
    intra4(key, up);
  }

  // ---- cumsum: thread-local scan + wave shuffle scan + 4-entry LDS hop ----
  float loc[EPT];
  float run = 0.f;
#pragma unroll
  for (int c = 0; c < EPT; ++c) {
    unsigned si = (unsigned)(key[c] & 0xffffffffu);
    run += wr[si];               // 16 KB row gather: L1/L2-hot
    loc[c] = run;
  }
  float tot = run, pref = run;
#pragma unroll
  for (int off = 1; off < 64; off <<= 1) {
    float v = __shfl_up(pref, off);
    if (lane >= off) pref += v;
  }
  if (lane == 63) wtot[wave] = pref;
  __syncthreads();
  float wpre = 0.f;
#pragma unroll
  for (int wv = 0; wv < 4; ++wv) wpre += (wv < wave) ? wtot[wv] : 0.f;
  float base = wpre + (pref - tot);

  // write sorted xs/ys (aliases su; all su reads complete before last barrier)
#pragma unroll
  for (int c = 0; c < EPT; ++c) {
    int i = 16 * tid + c;
    xs[i] = __uint_as_float((unsigned)(key[c] >> 32));
    ys[i] = base + loc[c];
  }
  __syncthreads();

  // ---- 256-bucket search LUT: lut[k] = lower_bound(xs, k/256) ----
  lut[tid] = lower_bound_f(xs, 0, NCOL, (float)tid * (1.0f / 256.0f));
  if (tid == 0) lut[256] = lower_bound_f(xs, 0, NCOL, 1.0f);
  __syncthreads();

  // ---- stage 1: ecdf[j] = floor(xnew) + interp1d(xs, ys, frac(xnew)) ----
#pragma unroll
  for (int s = 0; s < N3 / T; ++s) {
    int j = tid + s * T;
    float xnew = -1.0f + (3.0f * (float)j) / 3071.0f;
    float ix = floorf(xnew);
    float rest = xnew - ix;
    int k = (int)(rest * 256.0f);
    k = k > 255 ? 255 : k;
    int lo = lower_bound_f(xs, lut[k], lut[k + 1], rest);
    int ind = lo - 1;
    ind = ind < 0 ? 0 : (ind > NCOL - 2 ? NCOL - 2 : ind);
    float x0 = xs[ind], x1v = xs[ind + 1];
    float y0 = ys[ind], y1v = ys[ind + 1];
    float slope = (y1v - y0) / (FEPS + (x1v - x0));
    ecdf[j] = ix + (y0 + slope * (rest - x0));
  }
  __syncthreads();

  // ---- stage 2: inverse-CDF embedding + circular cost partial sum ----
  float alpha = s_alpha;
  float acc = 0.f;
#pragma unroll
  for (int s = 0; s < NG / T; ++s) {
    int kq = tid + s * T;
    float xg = (float)kq / 1024.0f;
    float q = xg - alpha;
    int lo = lower_bound_f(ecdf, 0, N3, q);
    int ind = lo - 1;
    ind = ind < 0 ? 0 : (ind > N3 - 2 ? N3 - 2 : ind);
    float e0 = ecdf[ind], e1 = ecdf[ind + 1];
    float y0 = -1.0f + (3.0f * (float)ind) / 3071.0f;
    float y1 = -1.0f + (3.0f * (float)(ind + 1)) / 3071.0f;
    float slope = (y1 - y0) / (FEPS + (e1 - e0));
    float emb = y0 + slope * (q - e0) - xg;
    float a = fabsf(emb);
    float m = fminf(a, 1.0f - a);
    acc += m * m;
  }
#pragma unroll
  for (int off = 32; off > 0; off >>= 1) acc += __shfl_down(acc, off);
  if (lane == 0) red1[wave] = acc;
  __syncthreads();
  if (tid == 0) rowsum[row] = red1[0] + red1[1] + red1[2] + red1[3];
}

__global__ __launch_bounds__(256) void lcot_final(const float* __restrict__ rowsum,
                                                  float* __restrict__ out) {
  __shared__ float red[4];
  int t = threadIdx.x;
  float s = 0.f;
  for (int i = t; i < L; i += 256) s += rowsum[i];
#pragma unroll
  for (int off = 32; off > 0; off >>= 1) s += __shfl_down(s, off);
  if ((t & 63) == 0) red[t >> 6] = s;
  __syncthreads();
  if (t == 0) {
    float tot = red[0] + red[1] + red[2] + red[3];
    out[0] = sqrtf(tot / (float)L + 1e-8f);
  }
}

extern "C" void kernel_launch(void* const* d_in, const int* in_sizes, int n_in,
                              void* d_out, int out_size, void* d_ws, size_t ws_size,
                              hipStream_t stream) {
  const float* X = (const float*)d_in[0];
  const float* W = (const float*)d_in[1];
  float* rowsum = (float*)d_ws;  // 2048 floats
  size_t shbytes = (size_t)NCOL * 8 + (size_t)N3 * 4 + 257 * 4;  // 46084 B
  hipLaunchKernelGGL(lcot_rows, dim3(L), dim3(T), shbytes, stream, X, W, rowsum);
  hipLaunchKernelGGL(lcot_final, dim3(1), dim3(256), 0, stream,
                     (const float*)rowsum, (float*)d_out);
}

// Round 3
// 194.527 us; speedup vs baseline: 9.2437x; 1.8581x over previous
//
#include <hip/hip_runtime.h>
#include <math.h>

#define L    2048
#define NCOL 4096
#define NG   1024
#define N3   3072
#define T    256
#define EPT  16           // NCOL / T
#define NB   2048         // buckets (exact: floor(x*2048), power-of-2 mult)
#define BPT  (NB / T)     // 8 buckets per thread in the scan
#define FEPS 1.1920929e-07f

typedef unsigned long long u64;

__device__ __forceinline__ int lower_bound_f(const float* a, int lo, int hi, float v) {
  // exact replica of numpy's npy_binsearch (side='left') on [lo,hi)
  while (lo < hi) {
    int mid = (lo + hi) >> 1;
    if (a[mid] < v) lo = mid + 1; else hi = mid;
  }
  return lo;
}

__device__ __forceinline__ int bucket_of(u64 k) {
  float f = __uint_as_float((unsigned)(k >> 32));
  int b = (int)(f * (float)NB);          // exact: mult by 2^11
  return b > NB - 1 ? NB - 1 : b;
}

__global__ __launch_bounds__(T, 3) void lcot_rows(const float* __restrict__ X,
                                                  const float* __restrict__ W,
                                                  float* __restrict__ rowsum) {
  extern __shared__ char smem[];
  u64*   pairs = (u64*)smem;                      // 32 KB; aliased by xs/ys later
  float* xs    = (float*)smem;                    // sorted x (alias)
  float* ys    = xs + NCOL;                       // sorted w -> CDF (alias)
  int*   cnt   = (int*)(smem + 32768);            // 2049 ints (base after scan)
  float* ecdf  = (float*)(smem + 32768 + 8200);   // 3072 floats

  __shared__ float redA[4], redB[4], fwt[4];
  __shared__ int   iwt[4];
  __shared__ float s_alpha;

  const int tid  = threadIdx.x;
  const int lane = tid & 63;
  const int wave = tid >> 6;
  const int row  = blockIdx.x;
  const float* xr = X + (size_t)row * NCOL;
  const float* wr = W + (size_t)row * NCOL;

  // ---- zero histogram ----
#pragma unroll
  for (int i = 0; i < BPT; ++i) cnt[tid + i * T] = 0;

  // ---- load 16 consecutive elems, pack stable keys, alpha partials ----
  u64 key[EPT]; float wv[EPT];
  float sxw = 0.f, sw = 0.f;
  const float4* xr4 = (const float4*)xr;
  const float4* wr4 = (const float4*)wr;
#pragma unroll
  for (int c = 0; c < 4; ++c) {
    float4 xv = xr4[tid * 4 + c];
    float4 ww = wr4[tid * 4 + c];
    sxw += xv.x * ww.x + xv.y * ww.y + xv.z * ww.z + xv.w * ww.w;
    sw  += ww.x + ww.y + ww.z + ww.w;
    int b = 16 * tid + 4 * c;
    key[4*c+0] = ((u64)__float_as_uint(xv.x) << 32) | (unsigned)(b + 0);
    key[4*c+1] = ((u64)__float_as_uint(xv.y) << 32) | (unsigned)(b + 1);
    key[4*c+2] = ((u64)__float_as_uint(xv.z) << 32) | (unsigned)(b + 2);
    key[4*c+3] = ((u64)__float_as_uint(xv.w) << 32) | (unsigned)(b + 3);
    wv[4*c+0] = ww.x; wv[4*c+1] = ww.y; wv[4*c+2] = ww.z; wv[4*c+3] = ww.w;
  }
#pragma unroll
  for (int off = 32; off > 0; off >>= 1) {
    sxw += __shfl_down(sxw, off);
    sw  += __shfl_down(sw, off);
  }
  if (lane == 0) { redA[wave] = sxw; redB[wave] = sw; }
  __syncthreads();   // zeroed cnt visible; redA/redB visible

  // ---- histogram: order-within-bucket via atomic return ----
  int ord[EPT];
#pragma unroll
  for (int e = 0; e < EPT; ++e) ord[e] = atomicAdd(&cnt[bucket_of(key[e])], 1);
  __syncthreads();
  if (tid == 0)
    s_alpha = (redA[0] + redA[1] + redA[2] + redA[3]) /
              (redB[0] + redB[1] + redB[2] + redB[3]) - 0.5f;

  // ---- exclusive scan of 2048 counts -> bucket bases (in place) ----
  int c8[BPT];
  int runi = 0;
#pragma unroll
  for (int j = 0; j < BPT; ++j) { c8[j] = cnt[tid * BPT + j]; runi += c8[j]; }
  int toti = runi, prei = runi;
#pragma unroll
  for (int off = 1; off < 64; off <<= 1) {
    int v = __shfl_up(prei, off);
    if (lane >= off) prei += v;
  }
  if (lane == 63) iwt[wave] = prei;
  __syncthreads();
  int wpre = 0;
#pragma unroll
  for (int w2 = 0; w2 < 4; ++w2) wpre += (w2 < wave) ? iwt[w2] : 0;
  int acc = wpre + prei - toti;
#pragma unroll
  for (int j = 0; j < BPT; ++j) { int t2 = acc; acc += c8[j]; cnt[tid * BPT + j] = t2; }
  if (tid == T - 1) cnt[NB] = acc;   // = 4096
  __syncthreads();

  // ---- scatter keys into bucket slots ----
#pragma unroll
  for (int e = 0; e < EPT; ++e) pairs[cnt[bucket_of(key[e])] + ord[e]] = key[e];
  __syncthreads();

  // ---- exact stable rank within bucket (strict u64 compare, idx tiebreak) ----
  int p[EPT];
#pragma unroll
  for (int e = 0; e < EPT; ++e) {
    int b = bucket_of(key[e]);
    int lo = cnt[b], m = cnt[b + 1] - lo;
    int r = 0;
    for (int q = 0; q < m; ++q) r += (pairs[lo + q] < key[e]) ? 1 : 0;
    p[e] = lo + r;
  }
  __syncthreads();   // all pairs reads done before aliasing writes

  // ---- place sorted x and w ----
#pragma unroll
  for (int e = 0; e < EPT; ++e) {
    xs[p[e]] = __uint_as_float((unsigned)(key[e] >> 32));
    ys[p[e]] = wv[e];
  }
  __syncthreads();

  // ---- cumsum of sorted weights (in place in ys) ----
  float lw[EPT];
  {
    const float4* y4 = (const float4*)(ys + 16 * tid);
    float4 a0 = y4[0], a1 = y4[1], a2 = y4[2], a3 = y4[3];
    lw[0]=a0.x; lw[1]=a0.y; lw[2]=a0.z; lw[3]=a0.w;
    lw[4]=a1.x; lw[5]=a1.y; lw[6]=a1.z; lw[7]=a1.w;
    lw[8]=a2.x; lw[9]=a2.y; lw[10]=a2.z; lw[11]=a2.w;
    lw[12]=a3.x; lw[13]=a3.y; lw[14]=a3.z; lw[15]=a3.w;
  }
  float runf = 0.f;
#pragma unroll
  for (int c = 0; c < EPT; ++c) { runf += lw[c]; lw[c] = runf; }
  float totf = runf, pref = runf;
#pragma unroll
  for (int off = 1; off < 64; off <<= 1) {
    float v = __shfl_up(pref, off);
    if (lane >= off) pref += v;
  }
  if (lane == 63) fwt[wave] = pref;
  __syncthreads();
  float wpf = 0.f;
#pragma unroll
  for (int w2 = 0; w2 < 4; ++w2) wpf += (w2 < wave) ? fwt[w2] : 0.f;
  float basef = wpf + pref - totf;
  {
    float4* y4 = (float4*)(ys + 16 * tid);
    y4[0] = make_float4(basef+lw[0],  basef+lw[1],  basef+lw[2],  basef+lw[3]);
    y4[1] = make_float4(basef+lw[4],  basef+lw[5],  basef+lw[6],  basef+lw[7]);
    y4[2] = make_float4(basef+lw[8],  basef+lw[9],  basef+lw[10], basef+lw[11]);
    y4[3] = make_float4(basef+lw[12], basef+lw[13], basef+lw[14], basef+lw[15]);
  }
  __syncthreads();

  // ---- stage 1: ecdf[j]; bucket bases give exact lower_bound bracket ----
#pragma unroll
  for (int s = 0; s < N3 / T; ++s) {
    int j = tid + s * T;
    float xnew = -1.0f + (3.0f * (float)j) / 3071.0f;
    float ix = floorf(xnew);
    float rest = xnew - ix;                  // in [0,1)
    int k = (int)(rest * (float)NB);         // exact
    k = k > NB - 1 ? NB - 1 : k;
    int lo = lower_bound_f(xs, cnt[k], cnt[k + 1], rest);
    int ind = lo - 1;
    ind = ind < 0 ? 0 : (ind > NCOL - 2 ? NCOL - 2 : ind);
    float x0 = xs[ind], x1v = xs[ind + 1];
    float y0 = ys[ind], y1v = ys[ind + 1];
    float slope = (y1v - y0) / (FEPS + (x1v - x0));
    ecdf[j] = ix + (y0 + slope * (rest - x0));
  }
  __syncthreads();

  // ---- stage 2: inverse-CDF embedding + circular cost partial sum ----
  float alpha = s_alpha;
  float accf = 0.f;
#pragma unroll
  for (int s = 0; s < NG / T; ++s) {
    int kq = tid + s * T;
    float xg = (float)kq / 1024.0f;
    float q = xg - alpha;
    int lo = lower_bound_f(ecdf, 0, N3, q);
    int ind = lo - 1;
    ind = ind < 0 ? 0 : (ind > N3 - 2 ? N3 - 2 : ind);
    float e0 = ecdf[ind], e1 = ecdf[ind + 1];
    float y0 = -1.0f + (3.0f * (float)ind) / 3071.0f;
    float y1 = -1.0f + (3.0f * (float)(ind + 1)) / 3071.0f;
    float slope = (y1 - y0) / (FEPS + (e1 - e0));
    float emb = y0 + slope * (q - e0) - xg;
    float a = fabsf(emb);
    float m = fminf(a, 1.0f - a);
    accf += m * m;
  }
#pragma unroll
  for (int off = 32; off > 0; off >>= 1) accf += __shfl_down(accf, off);
  if (lane == 0) redA[wave] = accf;
  __syncthreads();
  if (tid == 0) rowsum[row] = redA[0] + redA[1] + redA[2] + redA[3];
}

__global__ __launch_bounds__(256) void lcot_final(const float* __restrict__ rowsum,
                                                  float* __restrict__ out) {
  __shared__ float red[4];
  int t = threadIdx.x;
  float s = 0.f;
  for (int i = t; i < L; i += 256) s += rowsum[i];
#pragma unroll
  for (int off = 32; off > 0; off >>= 1) s += __shfl_down(s, off);
  if ((t & 63) == 0) red[t >> 6] = s;
  __syncthreads();
  if (t == 0) {
    float tot = red[0] + red[1] + red[2] + red[3];
    out[0] = sqrtf(tot / (float)L + 1e-8f);
  }
}

extern "C" void kernel_launch(void* const* d_in, const int* in_sizes, int n_in,
                              void* d_out, int out_size, void* d_ws, size_t ws_size,
                              hipStream_t stream) {
  const float* X = (const float*)d_in[0];
  const float* W = (const float*)d_in[1];
  float* rowsum = (float*)d_ws;  // 2048 floats
  size_t shbytes = 32768 + 8200 + (size_t)N3 * 4;  // 53,256 B -> 3 blocks/CU
  hipLaunchKernelGGL(lcot_rows, dim3(L), dim3(T), shbytes, stream, X, W, rowsum);
  hipLaunchKernelGGL(lcot_final, dim3(1), dim3(256), 0, stream,
                     (const float*)rowsum, (float*)d_out);
}

// Round 4
// 189.709 us; speedup vs baseline: 9.4784x; 1.0254x over previous
//
#include <hip/hip_runtime.h>
#include <math.h>

#define L    2048
#define NCOL 4096
#define NG   1024
#define N3   3072
#define T    512
#define NW   8            // waves per block
#define EPT  8            // NCOL / T
#define NB   2048         // buckets (exact: floor(x*2048), power-of-2 mult)
#define BPT  (NB / T)     // 4 buckets per thread in the scan
#define FEPS 1.1920929e-07f

typedef unsigned long long u64;

__device__ __forceinline__ int lower_bound_f(const float* a, int lo, int hi, float v) {
  // exact replica of numpy's npy_binsearch (side='left') on [lo,hi)
  while (lo < hi) {
    int mid = (lo + hi) >> 1;
    if (a[mid] < v) lo = mid + 1; else hi = mid;
  }
  return lo;
}

__device__ __forceinline__ int bucket_of(u64 k) {
  float f = __uint_as_float((unsigned)(k >> 32));
  int b = (int)(f * (float)NB);          // exact: mult by 2^11
  return b > NB - 1 ? NB - 1 : b;
}

__global__ __launch_bounds__(T, 2) void lcot_rows(const float* __restrict__ X,
                                                  const float* __restrict__ W,
                                                  float* __restrict__ rowsum) {
  extern __shared__ char smem[];
  u64*   pairs = (u64*)smem;                      // 32 KB; aliased by xs/ys later
  float* xs    = (float*)smem;                    // sorted x (alias)
  float* ys    = xs + NCOL;                       // sorted w -> CDF (alias)
  int*   cnt   = (int*)(smem + 32768);            // 2049 ints (bases after scan)
  float* ecdf  = (float*)(smem + 32768 + 8208);   // 3072 floats @ 40976
  unsigned short* lut2 = (unsigned short*)(smem + 32768 + 8208 + 12288); // 257 u16

  __shared__ float redA[NW], redB[NW], fwt[NW];
  __shared__ int   iwt[NW];
  __shared__ float s_alpha;

  const int tid  = threadIdx.x;
  const int lane = tid & 63;
  const int wave = tid >> 6;
  const int row  = blockIdx.x;
  const float* xr = X + (size_t)row * NCOL;
  const float* wr = W + (size_t)row * NCOL;

  // ---- zero histogram ----
#pragma unroll
  for (int i = 0; i < BPT; ++i) cnt[tid + i * T] = 0;

  // ---- load 8 consecutive elems, pack stable keys, alpha partials ----
  u64 key[EPT]; float wv[EPT];
  float sxw = 0.f, sw = 0.f;
  const float4* xr4 = (const float4*)xr;
  const float4* wr4 = (const float4*)wr;
#pragma unroll
  for (int c = 0; c < 2; ++c) {
    float4 xv = xr4[tid * 2 + c];
    float4 ww = wr4[tid * 2 + c];
    sxw += xv.x * ww.x + xv.y * ww.y + xv.z * ww.z + xv.w * ww.w;
    sw  += ww.x + ww.y + ww.z + ww.w;
    int b = 8 * tid + 4 * c;
    key[4*c+0] = ((u64)__float_as_uint(xv.x) << 32) | (unsigned)(b + 0);
    key[4*c+1] = ((u64)__float_as_uint(xv.y) << 32) | (unsigned)(b + 1);
    key[4*c+2] = ((u64)__float_as_uint(xv.z) << 32) | (unsigned)(b + 2);
    key[4*c+3] = ((u64)__float_as_uint(xv.w) << 32) | (unsigned)(b + 3);
    wv[4*c+0] = ww.x; wv[4*c+1] = ww.y; wv[4*c+2] = ww.z; wv[4*c+3] = ww.w;
  }
#pragma unroll
  for (int off = 32; off > 0; off >>= 1) {
    sxw += __shfl_down(sxw, off);
    sw  += __shfl_down(sw, off);
  }
  if (lane == 0) { redA[wave] = sxw; redB[wave] = sw; }
  __syncthreads();   // zeroed cnt visible; redA/redB visible

  // ---- histogram: order-within-bucket via atomic return ----
  int ord[EPT];
#pragma unroll
  for (int e = 0; e < EPT; ++e) ord[e] = atomicAdd(&cnt[bucket_of(key[e])], 1);
  __syncthreads();
  if (tid == 0) {
    float a = 0.f, b = 0.f;
#pragma unroll
    for (int i = 0; i < NW; ++i) { a += redA[i]; b += redB[i]; }
    s_alpha = a / b - 0.5f;
  }

  // ---- exclusive scan of 2048 counts -> bucket bases (in place) ----
  int c4[BPT];
  int runi = 0;
#pragma unroll
  for (int j = 0; j < BPT; ++j) { c4[j] = cnt[tid * BPT + j]; runi += c4[j]; }
  int toti = runi, prei = runi;
#pragma unroll
  for (int off = 1; off < 64; off <<= 1) {
    int v = __shfl_up(prei, off);
    if (lane >= off) prei += v;
  }
  if (lane == 63) iwt[wave] = prei;
  __syncthreads();   // also: all cnt reads complete before in-place writes
  int wpre = 0;
#pragma unroll
  for (int w2 = 0; w2 < NW; ++w2) wpre += (w2 < wave) ? iwt[w2] : 0;
  int acc = wpre + prei - toti;
#pragma unroll
  for (int j = 0; j < BPT; ++j) { int t2 = acc; acc += c4[j]; cnt[tid * BPT + j] = t2; }
  if (tid == T - 1) cnt[NB] = acc;   // = 4096
  __syncthreads();

  // ---- scatter keys into bucket slots ----
#pragma unroll
  for (int e = 0; e < EPT; ++e) pairs[cnt[bucket_of(key[e])] + ord[e]] = key[e];
  __syncthreads();

  // ---- exact stable rank within bucket (strict u64 compare, idx tiebreak) ----
  int p[EPT];
#pragma unroll
  for (int e = 0; e < EPT; ++e) {
    int b = bucket_of(key[e]);
    int lo = cnt[b], m = cnt[b + 1] - lo;
    int r = 0;
    for (int q = 0; q < m; ++q) r += (pairs[lo + q] < key[e]) ? 1 : 0;
    p[e] = lo + r;
  }
  __syncthreads();   // all pairs reads done before aliasing writes

  // ---- place sorted x and w ----
#pragma unroll
  for (int e = 0; e < EPT; ++e) {
    xs[p[e]] = __uint_as_float((unsigned)(key[e] >> 32));
    ys[p[e]] = wv[e];
  }
  __syncthreads();

  // ---- cumsum of sorted weights (in place in ys) ----
  float lw[EPT];
  {
    const float4* y4 = (const float4*)(ys + EPT * tid);
    float4 a0 = y4[0], a1 = y4[1];
    lw[0]=a0.x; lw[1]=a0.y; lw[2]=a0.z; lw[3]=a0.w;
    lw[4]=a1.x; lw[5]=a1.y; lw[6]=a1.z; lw[7]=a1.w;
  }
  float runf = 0.f;
#pragma unroll
  for (int c = 0; c < EPT; ++c) { runf += lw[c]; lw[c] = runf; }
  float totf = runf, pref = runf;
#pragma unroll
  for (int off = 1; off < 64; off <<= 1) {
    float v = __shfl_up(pref, off);
    if (lane >= off) pref += v;
  }
  if (lane == 63) fwt[wave] = pref;
  __syncthreads();
  float wpf = 0.f;
#pragma unroll
  for (int w2 = 0; w2 < NW; ++w2) wpf += (w2 < wave) ? fwt[w2] : 0.f;
  float basef = wpf + pref - totf;
  {
    float4* y4 = (float4*)(ys + EPT * tid);
    y4[0] = make_float4(basef+lw[0], basef+lw[1], basef+lw[2], basef+lw[3]);
    y4[1] = make_float4(basef+lw[4], basef+lw[5], basef+lw[6], basef+lw[7]);
  }
  __syncthreads();

  // ---- stage 1: ecdf[j]; bucket bases give exact lower_bound bracket ----
#pragma unroll
  for (int s = 0; s < N3 / T; ++s) {
    int j = tid + s * T;
    float xnew = -1.0f + (3.0f * (float)j) / 3071.0f;
    float ix = floorf(xnew);
    float rest = xnew - ix;                  // in [0,1)
    int k = (int)(rest * (float)NB);         // exact
    k = k > NB - 1 ? NB - 1 : k;
    int lo = lower_bound_f(xs, cnt[k], cnt[k + 1], rest);
    int ind = lo - 1;
    ind = ind < 0 ? 0 : (ind > NCOL - 2 ? NCOL - 2 : ind);
    float x0 = xs[ind], x1v = xs[ind + 1];
    float y0 = ys[ind], y1v = ys[ind + 1];
    float slope = (y1v - y0) / (FEPS + (x1v - x0));
    ecdf[j] = ix + (y0 + slope * (rest - x0));
  }
  __syncthreads();

  // ---- stage-2 value LUT over ecdf range [-1,2): 257 brackets ----
  if (tid < 257) {
    float v = -1.0f + 3.0f * (float)tid * (1.0f / 256.0f);
    lut2[tid] = (unsigned short)lower_bound_f(ecdf, 0, N3, v);
  }
  __syncthreads();

  // ---- stage 2: inverse-CDF embedding + circular cost partial sum ----
  float alpha = s_alpha;
  float accf = 0.f;
#pragma unroll
  for (int s = 0; s < NG / T; ++s) {
    int kq = tid + s * T;
    float xg = (float)kq / 1024.0f;
    float q = xg - alpha;
    int k2 = (int)floorf((q + 1.0f) * (256.0f / 3.0f));
    k2 = k2 < 0 ? 0 : (k2 > 255 ? 255 : k2);
    int blo = k2 > 0 ? k2 - 1 : 0;           // widen ±1: immune to fp rounding of k2
    int bhi = k2 < 254 ? k2 + 2 : 256;
    int lo = lower_bound_f(ecdf, lut2[blo], lut2[bhi], q);
    int ind = lo - 1;
    ind = ind < 0 ? 0 : (ind > N3 - 2 ? N3 - 2 : ind);
    float e0 = ecdf[ind], e1 = ecdf[ind + 1];
    float y0 = -1.0f + (3.0f * (float)ind) / 3071.0f;
    float y1 = -1.0f + (3.0f * (float)(ind + 1)) / 3071.0f;
    float slope = (y1 - y0) / (FEPS + (e1 - e0));
    float emb = y0 + slope * (q - e0) - xg;
    float a = fabsf(emb);
    float m = fminf(a, 1.0f - a);
    accf += m * m;
  }
#pragma unroll
  for (int off = 32; off > 0; off >>= 1) accf += __shfl_down(accf, off);
  if (lane == 0) redA[wave] = accf;
  __syncthreads();
  if (tid == 0) {
    float s = 0.f;
#pragma unroll
    for (int i = 0; i < NW; ++i) s += redA[i];
    rowsum[row] = s;
  }
}

__global__ __launch_bounds__(256) void lcot_final(const float* __restrict__ rowsum,
                                                  float* __restrict__ out) {
  __shared__ float red[4];
  int t = threadIdx.x;
  float s = 0.f;
  for (int i = t; i < L; i += 256) s += rowsum[i];
#pragma unroll
  for (int off = 32; off > 0; off >>= 1) s += __shfl_down(s, off);
  if ((t & 63) == 0) red[t >> 6] = s;
  __syncthreads();
  if (t == 0) {
    float tot = red[0] + red[1] + red[2] + red[3];
    out[0] = sqrtf(tot / (float)L + 1e-8f);
  }
}

extern "C" void kernel_launch(void* const* d_in, const int* in_sizes, int n_in,
                              void* d_out, int out_size, void* d_ws, size_t ws_size,
                              hipStream_t stream) {
  const float* X = (const float*)d_in[0];
  const float* W = (const float*)d_in[1];
  float* rowsum = (float*)d_ws;  // 2048 floats
  // 32768 (pairs/xs/ys) + 8208 (cnt, padded) + 12288 (ecdf) + 520 (lut2) = 53,784 B
  // -> 3 blocks/CU (54.6 KB/block ceiling), 24 waves/CU
  size_t shbytes = 32768 + 8208 + 12288 + 520;
  hipLaunchKernelGGL(lcot_rows, dim3(L), dim3(T), shbytes, stream, X, W, rowsum);
  hipLaunchKernelGGL(lcot_final, dim3(1), dim3(256), 0, stream,
                     (const float*)rowsum, (float*)d_out);
}